// Round 8
// baseline (733.692 us; speedup 1.0000x reference)
//
#include <hip/hip_runtime.h>
#include <math.h>

typedef unsigned short u16;
typedef unsigned int   u32;
typedef __attribute__((ext_vector_type(8))) short short8;
typedef __attribute__((ext_vector_type(4))) float floatx4;

#define MFMA16(a, b, c) __builtin_amdgcn_mfma_f32_16x16x32_bf16(a, b, c, 0, 0, 0)
#define LOG2E 1.4426950408889634f

__device__ __forceinline__ float b2f(u16 b) { return __uint_as_float(((u32)b) << 16); }
__device__ __forceinline__ u16 f2b(float f) {
  u32 x = __float_as_uint(f);
  return (u16)((x + 0x7FFFu + ((x >> 16) & 1u)) >> 16);
}
// single-instruction exp2 (args bounded <= +8 by defer-max; very negative flushes to 0)
__device__ __forceinline__ float fexp2(float x) {
  float r;
  asm("v_exp_f32 %0, %1" : "=v"(r) : "v"(x));
  return r;
}
__device__ __forceinline__ short8 pack8(float4 a, float4 b) {
  short8 r;
  r[0] = (short)f2b(a.x); r[1] = (short)f2b(a.y); r[2] = (short)f2b(a.z); r[3] = (short)f2b(a.w);
  r[4] = (short)f2b(b.x); r[5] = (short)f2b(b.y); r[6] = (short)f2b(b.z); r[7] = (short)f2b(b.w);
  return r;
}
// async 16B global->LDS (wave-uniform LDS base + lane*16; global addr is per-lane)
__device__ __forceinline__ void gload16(const u16* g, u16* l) {
  __builtin_amdgcn_global_load_lds(
      (const __attribute__((address_space(1))) u32*)g,
      (__attribute__((address_space(3))) u32*)l, 16, 0, 0);
}
// GEMM LDS swizzle: row r of 32 u16, chunk c (0..3, 16B each).
// phys slot within 128B line: ((r&1)*4 | c) ^ ((r>>1)&7)  -> 64 lanes uniform over 8 slots.
__device__ __forceinline__ int swzg(int r, int c) {
  return ((r >> 1) << 6) + (((((r & 1) << 2) | c) ^ ((r >> 1) & 7)) << 3);
}

// ---------------- prep: column bias (log2-domain) and value gate ----------------
__global__ void prep_kernel(const float* __restrict__ ppr, const float* __restrict__ trust,
                            const float* __restrict__ plpa, const float* __restrict__ ptsc,
                            const int* __restrict__ pnc,
                            float* __restrict__ colbias, float* __restrict__ vgate)
{
  const int i = blockIdx.x * 256 + threadIdx.x;   // grid 8 -> 2048
  const int n_ctx = pnc[0];
  const float lpa = plpa[0], ts = ptsc[0];
  if (i < 2048) {
    float cb = 0.0f, g = 1.0f;
    if (i < n_ctx) {
      cb = -lpa * logf(fmaxf(ppr[i], 1e-8f)) * LOG2E;
      g = 1.0f / (1.0f + expf(-ts * trust[i]));
    }
    colbias[i] = cb;
    vgate[i] = g;
  }
}

// ---------------- fp32 -> bf16 conversion passes ----------------
__global__ __launch_bounds__(256) void convert1(const float* __restrict__ X, const float* __restrict__ Wi,
                                                u16* __restrict__ Xb, u16* __restrict__ Wib)
{
  const size_t i = ((size_t)blockIdx.x * 256 + threadIdx.x) * 8;  // grid 5632 covers 11,534,336
  const float* src;
  u16* dst;
  if (i < 8388608) { src = X + i; dst = Xb + i; }
  else { src = Wi + (i - 8388608); dst = Wib + (i - 8388608); }
  float4 a = *(const float4*)src, b = *(const float4*)(src + 4);
  *(short8*)dst = pack8(a, b);
}

__global__ __launch_bounds__(256) void convert2(const float* __restrict__ Wo, u16* __restrict__ Wob)
{
  const size_t i = ((size_t)blockIdx.x * 256 + threadIdx.x) * 8;  // grid 512 -> 1,048,576
  float4 a = *(const float4*)(Wo + i), b = *(const float4*)(Wo + i + 4);
  *(short8*)(Wob + i) = pack8(a, b);
}

// ---------------- QKV projection: bf16 MFMA GEMM, DMA dbuf + swizzle ----------------
// q -> [bh][n][64]; k -> pre-scaled by 0.125*log2e; v -> gated, transposed [bh][d][2048]
__global__ __launch_bounds__(256, 4) void qkv_mfma(
    const u16* __restrict__ Xb, const u16* __restrict__ Wib, const float* __restrict__ bin,
    const float* __restrict__ vgate,
    u16* __restrict__ qW, u16* __restrict__ kW, u16* __restrict__ vT)
{
  __shared__ __align__(16) u16 SMEM[16384];     // 32 KB: [2][As 4096|Bs 4096]; epilogue T 64x136
  const int tid = threadIdx.x;
  const int wave = tid >> 6, lane = tid & 63;
  const int k15 = lane & 15, quad = lane >> 4;
  const int wm = wave & 1, wn = wave >> 1;
  const int m0 = blockIdx.y << 7, n0 = blockIdx.x << 7;

  // pre-swizzled DMA source: lane fetches the global chunk for its linear LDS slot
  const int line = lane >> 3;                   // 0..7 (128B line within a 1KB issue)
  const int sl = (lane & 7) ^ line;             // logical slot
  const int rloc = (line << 1) | (sl >> 2);     // 0..15 row within 16-row issue
  const int cch = (sl & 3) << 3;                // chunk u16 offset
  const u16* gA = Xb + (size_t)(m0 + (wave << 5) + rloc) * 1024 + cch;
  const u16* gB = Wib + (size_t)(n0 + (wave << 5) + rloc) * 1024 + cch;

#define STAGE(buf, k0s) do {                                                   \
    u16* As_ = SMEM + (buf) * 8192 + (wave << 10);                             \
    gload16(gA + (k0s), As_);                                                  \
    gload16(gA + (k0s) + 16 * 1024, As_ + 512);                                \
    gload16(gB + (k0s), As_ + 4096);                                           \
    gload16(gB + (k0s) + 16 * 1024, As_ + 4608);                               \
  } while (0)

  // loop-invariant frag LDS offsets
  int afo[4], bfo[4];
#pragma unroll
  for (int rt = 0; rt < 4; ++rt) afo[rt] = swzg(64 * wm + 16 * rt + k15, quad);
#pragma unroll
  for (int ct = 0; ct < 4; ++ct) bfo[ct] = 4096 + swzg(64 * wn + 16 * ct + k15, quad);

  floatx4 c[4][4];
#pragma unroll
  for (int i = 0; i < 4; ++i)
#pragma unroll
    for (int j = 0; j < 4; ++j) c[i][j] = (floatx4){0.f, 0.f, 0.f, 0.f};

  STAGE(0, 0);
  for (int k0 = 0; k0 < 1024; k0 += 32) {
    const int cur = (k0 >> 5) & 1;
    if (k0 < 992) {
      STAGE(cur ^ 1, k0 + 32);
      __builtin_amdgcn_sched_barrier(0);
      asm volatile("s_waitcnt vmcnt(4)" ::: "memory");  // cur's 4 landed; next's 4 in flight
    } else {
      __builtin_amdgcn_sched_barrier(0);
      asm volatile("s_waitcnt vmcnt(0)" ::: "memory");
    }
    __builtin_amdgcn_sched_barrier(0);
    __builtin_amdgcn_s_barrier();
    __builtin_amdgcn_sched_barrier(0);

    const u16* Base = SMEM + cur * 8192;
    short8 af[4], bf[4];
#pragma unroll
    for (int rt = 0; rt < 4; ++rt) af[rt] = *(const short8*)(Base + afo[rt]);
#pragma unroll
    for (int ct = 0; ct < 4; ++ct) bf[ct] = *(const short8*)(Base + bfo[ct]);
    __builtin_amdgcn_s_setprio(1);
#pragma unroll
    for (int rt = 0; rt < 4; ++rt)
#pragma unroll
      for (int ct = 0; ct < 4; ++ct)
        c[rt][ct] = MFMA16(af[rt], bf[ct], c[rt][ct]);
    __builtin_amdgcn_s_setprio(0);
    __builtin_amdgcn_sched_barrier(0);
    __builtin_amdgcn_s_barrier();               // reads of cur done before its overwrite
    __builtin_amdgcn_sched_barrier(0);
  }
#undef STAGE

  const int which = n0 >> 10;                   // 0=q 1=k 2=v (block never crosses)
  if (which < 2) {
    u16* dst0 = which ? kW : qW;
    const float ksc = which ? 0.125f * LOG2E : 1.0f;
#pragma unroll
    for (int ct = 0; ct < 4; ++ct) {
      const int e = n0 + 64 * wn + 16 * ct + k15;
      const float bb = bin[e];
      const int h = (e >> 6) & 15, d = e & 63;
#pragma unroll
      for (int rt = 0; rt < 4; ++rt)
#pragma unroll
        for (int r = 0; r < 4; ++r) {
          const int m = m0 + 64 * wm + 16 * rt + 4 * quad + r;
          const int b = m >> 11, n = m & 2047;
          dst0[(((size_t)(b * 16 + h)) * 2048 + n) * 64 + d] = f2b((c[rt][ct][r] + bb) * ksc);
        }
    }
  } else {
    // v: gate, transpose 128x64 half-tiles through LDS -> vT[bh][d][2048]
    const int b = m0 >> 11, nbase = m0 & 2047;
    u16* T = SMEM;                              // 64 x 136 u16
    for (int half = 0; half < 2; ++half) {
      __syncthreads();
      if (wn == half) {
#pragma unroll
        for (int ct = 0; ct < 4; ++ct) {
          const int el = 16 * ct + k15;
          const int e = n0 + 64 * half + el;
          const float bb = bin[e];
#pragma unroll
          for (int rt = 0; rt < 4; ++rt)
#pragma unroll
            for (int r = 0; r < 4; ++r) {
              const int ml = 64 * wm + 16 * rt + 4 * quad + r;
              T[el * 136 + ml] = f2b((c[rt][ct][r] + bb) * vgate[nbase + ml]);
            }
        }
      }
      __syncthreads();
#pragma unroll
      for (int uu = 0; uu < 4; ++uu) {
        const int u = tid + uu * 256;
        const int el = u >> 4, moct = u & 15;
        const int e = n0 + 64 * half + el;
        const int h = (e >> 6) & 15, d = e & 63;
        short8 vv = *(const short8*)(T + el * 136 + moct * 8);
        *(short8*)(vT + (((size_t)(b * 16 + h)) * 64 + d) * 2048 + nbase + moct * 8) = vv;
      }
    }
  }
}

// ---------------- Flash attention v9: barrier-free, zero-staging ----------------
// K/V for one head = 512 KB -> L2-resident (XCD-affine bh). All K/V/cb fragments
// read just-in-time from global (per-frag lifetime = 1 MFMA pair -> no spill risk,
// compiler-managed waitcnt). LDS = wave-private Ps only (8 KB). No barriers: waves
// free-run, mixing VALU/MFMA/VMEM phases. 16 q/wave, grid 2048 (32 qt x 64 bh).
__global__ __launch_bounds__(256, 6) void attn_mfma(
    const u16* __restrict__ qW, const u16* __restrict__ kW, const u16* __restrict__ vT,
    const float* __restrict__ colbias, u16* __restrict__ aO)
{
  __shared__ __align__(16) u16 Ps[4][1024];     // per-wave P [q 16][key 64], XOR-swizzled

  const int tid = threadIdx.x;
  const int wave = tid >> 6, lane = tid & 63;
  const int k15 = lane & 15, quad = lane >> 4;
  const int bid = blockIdx.x;
  const int bh = bid & 63, qt = bid >> 6;       // XCD-affine: all 32 q-tiles of bh on one XCD
  const size_t base = (size_t)bh * 2048 * 64;
  const size_t baseV = (size_t)bh * 64 * 2048;
  const int q0 = qt * 64 + wave * 16;

  // Ps swizzle (pure LDS-side, write and read use the same XOR)
  const int sw3 = (k15 & 7) << 3;
  const int cA = (quad * 8) ^ sw3;              // logical key chunk 0..31
  const int cB = (quad * 8 + 32) ^ sw3;         // logical key chunk 32..63

  const u16* gK = kW + base;                    // [key][64]
  const u16* gV = vT + baseV;                   // [d][2048]

  // Q fragments (B operand): col=q, k=d
  const u16* qp = qW + base + (size_t)(q0 + k15) * 64 + quad * 8;
  short8 qa0 = *(const short8*)qp;              // d 0..31
  short8 qa1 = *(const short8*)(qp + 32);       // d 32..63

  floatx4 o[4];
#pragma unroll
  for (int t = 0; t < 4; ++t) o[t] = (floatx4){0.f, 0.f, 0.f, 0.f};
  floatx4 l = (floatx4){0.f, 0.f, 0.f, 0.f};
  float m = -3.0e38f;

  u16* PsW = Ps[wave];
  const short8 ones8 = (short8){16256, 16256, 16256, 16256, 16256, 16256, 16256, 16256};

  for (int kb = 0; kb < 2048; kb += 64) {
    // colbias for this key tile (C-init per key row)
    float4 cb[4];
#pragma unroll
    for (int t = 0; t < 4; ++t)
      cb[t] = *(const float4*)(colbias + kb + 16 * t + 4 * quad);

    // S^T = K.Q^T ; K frags JIT from global (16 rows x 128B contiguous segments)
    floatx4 s[4];
    __builtin_amdgcn_s_setprio(1);
#pragma unroll
    for (int t = 0; t < 4; ++t) {
      const u16* kp = gK + (size_t)(kb + 16 * t + k15) * 64 + quad * 8;
      short8 ka0 = *(const short8*)kp;
      short8 ka1 = *(const short8*)(kp + 32);
      floatx4 ci = (floatx4){cb[t].x, cb[t].y, cb[t].z, cb[t].w};
      s[t] = MFMA16(ka0, qa0, ci);
      s[t] = MFMA16(ka1, qa1, s[t]);
    }
    __builtin_amdgcn_s_setprio(0);

    // per-lane softmax (log2 domain), defer-max (THR=8), pack P -> wave-private LDS
    {
      float mx = fmaxf(fmaxf(s[0][0], s[0][1]), fmaxf(s[0][2], s[0][3]));
#pragma unroll
      for (int t = 1; t < 4; ++t)
        mx = fmaxf(mx, fmaxf(fmaxf(s[t][0], s[t][1]), fmaxf(s[t][2], s[t][3])));
      mx = fmaxf(mx, __shfl_xor(mx, 16));
      mx = fmaxf(mx, __shfl_xor(mx, 32));
      if (__any(mx > m + 8.0f)) {
        const float mn = fmaxf(m, mx);
        const float al = fexp2(m - mn);
        m = mn;
        const float a0 = __shfl(al, 4 * quad + 0);
        const float a1 = __shfl(al, 4 * quad + 1);
        const float a2 = __shfl(al, 4 * quad + 2);
        const float a3 = __shfl(al, 4 * quad + 3);
        l[0] *= a0; l[1] *= a1; l[2] *= a2; l[3] *= a3;
#pragma unroll
        for (int t = 0; t < 4; ++t) {
          o[t][0] *= a0; o[t][1] *= a1; o[t][2] *= a2; o[t][3] *= a3;
        }
      }
#pragma unroll
      for (int t = 0; t < 4; ++t) {
        float p0 = fexp2(s[t][0] - m), p1 = fexp2(s[t][1] - m);
        float p2 = fexp2(s[t][2] - m), p3 = fexp2(s[t][3] - m);
        u32 lo = __builtin_amdgcn_perm(__float_as_uint(p1), __float_as_uint(p0), 0x07060302u);
        u32 hi = __builtin_amdgcn_perm(__float_as_uint(p3), __float_as_uint(p2), 0x07060302u);
        *(uint2*)(PsW + k15 * 64 + ((16 * t + 4 * quad) ^ sw3)) = (uint2){lo, hi};
      }
    }

    // P frags (wave-private LDS; DS ops in-order per wave, no barrier needed)
    short8 pa0 = *(const short8*)(PsW + k15 * 64 + cA);
    short8 pa1 = *(const short8*)(PsW + k15 * 64 + cB);
    // row-sum on the MFMA pipe: l += P . ones  (D-layout: row q = 4*quad+r)
    l = MFMA16(pa1, ones8, MFMA16(pa0, ones8, l));

    // O += P.V ; V frags JIT from global, per-t lifetime
    __builtin_amdgcn_s_setprio(1);
#pragma unroll
    for (int t = 0; t < 4; ++t) {
      const u16* vp = gV + (size_t)(16 * t + k15) * 2048 + kb + quad * 8;
      short8 vb0 = *(const short8*)vp;
      short8 vb1 = *(const short8*)(vp + 32);
      o[t] = MFMA16(pa0, vb0, o[t]);
      o[t] = MFMA16(pa1, vb1, o[t]);
    }
    __builtin_amdgcn_s_setprio(0);
  }

  // epilogue: l in D-layout; normalize, store aO [b][n][h*64+d]
  const int b = bh >> 4, h = bh & 15;
#pragma unroll
  for (int r = 0; r < 4; ++r) {
    const int q = q0 + 4 * quad + r;
    const float inv = 1.0f / l[r];
    u16* dst = aO + (size_t)(b * 2048 + q) * 1024 + h * 64;
#pragma unroll
    for (int t = 0; t < 4; ++t) dst[16 * t + k15] = f2b(o[t][r] * inv);
  }
}

// ---------------- Output projection v2: BM=64 x BN=128, 4 blocks/CU ----------------
// 4 waves as 1m x 4n; acc 4x2 (32 VGPR); grid (8,128)=1024 blocks; dbuf + vmcnt(3).
__global__ __launch_bounds__(256, 4) void oproj_mfma(
    const u16* __restrict__ A, const u16* __restrict__ Wob, const float* __restrict__ bout,
    float* __restrict__ out)
{
  __shared__ __align__(16) u16 SMEM[12288];     // 24 KB: [2][As 2048 | Bs 4096]
  const int tid = threadIdx.x;
  const int wave = tid >> 6, lane = tid & 63;
  const int k15 = lane & 15, quad = lane >> 4;
  const int m0 = blockIdx.y << 6, n0 = blockIdx.x << 7;

  const int line = lane >> 3;
  const int sl = (lane & 7) ^ line;
  const int rloc = (line << 1) | (sl >> 2);
  const int cch = (sl & 3) << 3;
  const u16* gA = A + (size_t)(m0 + (wave << 4) + rloc) * 1024 + cch;   // wave stages 16 A-rows
  const u16* gB = Wob + (size_t)(n0 + (wave << 5) + rloc) * 1024 + cch; // wave stages 32 B-rows

#define STAGE(buf, k0s) do {                                                   \
    u16* b_ = SMEM + (buf) * 6144;                                             \
    gload16(gA + (k0s), b_ + (wave << 9));                                     \
    gload16(gB + (k0s), b_ + 2048 + (wave << 10));                             \
    gload16(gB + (k0s) + 16 * 1024, b_ + 2048 + (wave << 10) + 512);           \
  } while (0)

  // loop-invariant frag LDS offsets (A rows 0..63; B rows = wave's 32 cols)
  int afo[4], bfo[2];
#pragma unroll
  for (int rt = 0; rt < 4; ++rt) afo[rt] = swzg(16 * rt + k15, quad);
#pragma unroll
  for (int ct = 0; ct < 2; ++ct) bfo[ct] = 2048 + swzg((wave << 5) + 16 * ct + k15, quad);

  floatx4 c[4][2];
#pragma unroll
  for (int i = 0; i < 4; ++i)
#pragma unroll
    for (int j = 0; j < 2; ++j) c[i][j] = (floatx4){0.f, 0.f, 0.f, 0.f};

  STAGE(0, 0);
  for (int k0 = 0; k0 < 1024; k0 += 32) {
    const int cur = (k0 >> 5) & 1;
    if (k0 < 992) {
      STAGE(cur ^ 1, k0 + 32);
      __builtin_amdgcn_sched_barrier(0);
      asm volatile("s_waitcnt vmcnt(3)" ::: "memory");  // cur's 3 landed; next's 3 in flight
    } else {
      __builtin_amdgcn_sched_barrier(0);
      asm volatile("s_waitcnt vmcnt(0)" ::: "memory");
    }
    __builtin_amdgcn_sched_barrier(0);
    __builtin_amdgcn_s_barrier();
    __builtin_amdgcn_sched_barrier(0);

    const u16* Base = SMEM + cur * 6144;
    short8 af[4], bf[2];
#pragma unroll
    for (int rt = 0; rt < 4; ++rt) af[rt] = *(const short8*)(Base + afo[rt]);
#pragma unroll
    for (int ct = 0; ct < 2; ++ct) bf[ct] = *(const short8*)(Base + bfo[ct]);
    __builtin_amdgcn_s_setprio(1);
#pragma unroll
    for (int rt = 0; rt < 4; ++rt)
#pragma unroll
      for (int ct = 0; ct < 2; ++ct)
        c[rt][ct] = MFMA16(af[rt], bf[ct], c[rt][ct]);
    __builtin_amdgcn_s_setprio(0);
    __builtin_amdgcn_sched_barrier(0);
    __builtin_amdgcn_s_barrier();
    __builtin_amdgcn_sched_barrier(0);
  }
#undef STAGE

#pragma unroll
  for (int ct = 0; ct < 2; ++ct) {
    const int e = n0 + (wave << 5) + 16 * ct + k15;
    const float bb = bout[e];
#pragma unroll
    for (int rt = 0; rt < 4; ++rt)
#pragma unroll
      for (int r = 0; r < 4; ++r) {
        const int m = m0 + 16 * rt + 4 * quad + r;
        out[(size_t)m * 1024 + e] = c[rt][ct][r] + bb;
      }
  }
}

extern "C" void kernel_launch(void* const* d_in, const int* in_sizes, int n_in,
                              void* d_out, int out_size, void* d_ws, size_t ws_size,
                              hipStream_t stream)
{
  const float* X     = (const float*)d_in[0];
  const int*   pnc   = (const int*)d_in[1];
  const float* ppr   = (const float*)d_in[2];
  const float* trust = (const float*)d_in[3];
  const float* Win   = (const float*)d_in[4];
  const float* bin   = (const float*)d_in[5];
  const float* Wout  = (const float*)d_in[6];
  const float* bout  = (const float*)d_in[7];
  const float* plpa  = (const float*)d_in[8];
  const float* ptsc  = (const float*)d_in[9];
  float* out = (float*)d_out;

  const size_t SZ = (size_t)64 * 2048 * 64;     // 8,388,608 elems = 16 MB bf16
  u16* Xb = (u16*)d_ws;                         // phase 1-2; aliased by aO in phase 3+
  u16* qW = Xb + SZ;
  u16* kW = qW + SZ;                            // phase 3; aliased by Wob in phase 4+
  u16* vT = kW + SZ;                            // [bh][d][2048]   (total ws = 64 MB)
  u16* aO = Xb;
  u16* Wob = kW;
  // scratch parked in d_out (fully overwritten by oproj at the end):
  float* colbias = (float*)d_out;               // [2048] (log2-domain)
  float* vgate   = colbias + 2048;              // [2048]
  u16*   Wib     = (u16*)(vgate + 2048);        // 3072x1024 bf16 = 6 MB

  prep_kernel<<<dim3(8), 256, 0, stream>>>(ppr, trust, plpa, ptsc, pnc, colbias, vgate);
  convert1<<<dim3(5632), 256, 0, stream>>>(X, Win, Xb, Wib);
  qkv_mfma<<<dim3(24, 64), 256, 0, stream>>>(Xb, Wib, bin, vgate, qW, kW, vT);
  attn_mfma<<<dim3(2048), 256, 0, stream>>>(qW, kW, vT, colbias, aO);
  convert2<<<dim3(512), 256, 0, stream>>>(Wout, Wob);
  oproj_mfma<<<dim3(8, 128), 256, 0, stream>>>(aO, Wob, bout, out);
}

// Round 10
// 300.184 us; speedup vs baseline: 2.4441x; 2.4441x over previous
//
#include <hip/hip_runtime.h>
#include <math.h>

typedef unsigned short u16;
typedef unsigned int   u32;
typedef __attribute__((ext_vector_type(8))) short short8;
typedef __attribute__((ext_vector_type(4))) float floatx4;

#define MFMA16(a, b, c) __builtin_amdgcn_mfma_f32_16x16x32_bf16(a, b, c, 0, 0, 0)
#define LOG2E 1.4426950408889634f

__device__ __forceinline__ float b2f(u16 b) { return __uint_as_float(((u32)b) << 16); }
__device__ __forceinline__ u16 f2b(float f) {
  u32 x = __float_as_uint(f);
  return (u16)((x + 0x7FFFu + ((x >> 16) & 1u)) >> 16);
}
// single-instruction exp2 (args bounded <= +8 by defer-max; very negative flushes to 0)
__device__ __forceinline__ float fexp2(float x) {
  float r;
  asm("v_exp_f32 %0, %1" : "=v"(r) : "v"(x));
  return r;
}
__device__ __forceinline__ short8 pack8(float4 a, float4 b) {
  short8 r;
  r[0] = (short)f2b(a.x); r[1] = (short)f2b(a.y); r[2] = (short)f2b(a.z); r[3] = (short)f2b(a.w);
  r[4] = (short)f2b(b.x); r[5] = (short)f2b(b.y); r[6] = (short)f2b(b.z); r[7] = (short)f2b(b.w);
  return r;
}
// async 16B global->LDS (wave-uniform LDS base + lane*16; global addr is per-lane)
__device__ __forceinline__ void gload16(const u16* g, u16* l) {
  __builtin_amdgcn_global_load_lds(
      (const __attribute__((address_space(1))) u32*)g,
      (__attribute__((address_space(3))) u32*)l, 16, 0, 0);
}
// GEMM LDS swizzle: row r of 32 u16, chunk c (0..3, 16B each).
// phys slot within 128B line: ((r&1)*4 | c) ^ ((r>>1)&7)  -> 64 lanes uniform over 8 slots.
__device__ __forceinline__ int swzg(int r, int c) {
  return ((r >> 1) << 6) + (((((r & 1) << 2) | c) ^ ((r >> 1) & 7)) << 3);
}

// ---------------- prep: column bias (log2-domain) and value gate ----------------
__global__ void prep_kernel(const float* __restrict__ ppr, const float* __restrict__ trust,
                            const float* __restrict__ plpa, const float* __restrict__ ptsc,
                            const int* __restrict__ pnc,
                            float* __restrict__ colbias, float* __restrict__ vgate)
{
  const int i = blockIdx.x * 256 + threadIdx.x;   // grid 8 -> 2048
  const int n_ctx = pnc[0];
  const float lpa = plpa[0], ts = ptsc[0];
  if (i < 2048) {
    float cb = 0.0f, g = 1.0f;
    if (i < n_ctx) {
      cb = -lpa * logf(fmaxf(ppr[i], 1e-8f)) * LOG2E;
      g = 1.0f / (1.0f + expf(-ts * trust[i]));
    }
    colbias[i] = cb;
    vgate[i] = g;
  }
}

// ---------------- fp32 -> bf16 conversion passes ----------------
__global__ __launch_bounds__(256) void convert1(const float* __restrict__ X, const float* __restrict__ Wi,
                                                u16* __restrict__ Xb, u16* __restrict__ Wib)
{
  const size_t i = ((size_t)blockIdx.x * 256 + threadIdx.x) * 8;  // grid 5632 covers 11,534,336
  const float* src;
  u16* dst;
  if (i < 8388608) { src = X + i; dst = Xb + i; }
  else { src = Wi + (i - 8388608); dst = Wib + (i - 8388608); }
  float4 a = *(const float4*)src, b = *(const float4*)(src + 4);
  *(short8*)dst = pack8(a, b);
}

__global__ __launch_bounds__(256) void convert2(const float* __restrict__ Wo, u16* __restrict__ Wob)
{
  const size_t i = ((size_t)blockIdx.x * 256 + threadIdx.x) * 8;  // grid 512 -> 1,048,576
  float4 a = *(const float4*)(Wo + i), b = *(const float4*)(Wo + i + 4);
  *(short8*)(Wob + i) = pack8(a, b);
}

// ---------------- QKV projection: bf16 MFMA GEMM, DMA dbuf + swizzle ----------------
// q -> [bh][n][64]; k -> pre-scaled by 0.125*log2e; v -> gated, transposed [bh][d][2048]
__global__ __launch_bounds__(256, 4) void qkv_mfma(
    const u16* __restrict__ Xb, const u16* __restrict__ Wib, const float* __restrict__ bin,
    const float* __restrict__ vgate,
    u16* __restrict__ qW, u16* __restrict__ kW, u16* __restrict__ vT)
{
  __shared__ __align__(16) u16 SMEM[16384];     // 32 KB: [2][As 4096|Bs 4096]; epilogue T 64x136
  const int tid = threadIdx.x;
  const int wave = tid >> 6, lane = tid & 63;
  const int k15 = lane & 15, quad = lane >> 4;
  const int wm = wave & 1, wn = wave >> 1;
  const int m0 = blockIdx.y << 7, n0 = blockIdx.x << 7;

  // pre-swizzled DMA source: lane fetches the global chunk for its linear LDS slot
  const int line = lane >> 3;                   // 0..7 (128B line within a 1KB issue)
  const int sl = (lane & 7) ^ line;             // logical slot
  const int rloc = (line << 1) | (sl >> 2);     // 0..15 row within 16-row issue
  const int cch = (sl & 3) << 3;                // chunk u16 offset
  const u16* gA = Xb + (size_t)(m0 + (wave << 5) + rloc) * 1024 + cch;
  const u16* gB = Wib + (size_t)(n0 + (wave << 5) + rloc) * 1024 + cch;

#define STAGE(buf, k0s) do {                                                   \
    u16* As_ = SMEM + (buf) * 8192 + (wave << 10);                             \
    gload16(gA + (k0s), As_);                                                  \
    gload16(gA + (k0s) + 16 * 1024, As_ + 512);                                \
    gload16(gB + (k0s), As_ + 4096);                                           \
    gload16(gB + (k0s) + 16 * 1024, As_ + 4608);                               \
  } while (0)

  // loop-invariant frag LDS offsets
  int afo[4], bfo[4];
#pragma unroll
  for (int rt = 0; rt < 4; ++rt) afo[rt] = swzg(64 * wm + 16 * rt + k15, quad);
#pragma unroll
  for (int ct = 0; ct < 4; ++ct) bfo[ct] = 4096 + swzg(64 * wn + 16 * ct + k15, quad);

  floatx4 c[4][4];
#pragma unroll
  for (int i = 0; i < 4; ++i)
#pragma unroll
    for (int j = 0; j < 4; ++j) c[i][j] = (floatx4){0.f, 0.f, 0.f, 0.f};

  STAGE(0, 0);
  for (int k0 = 0; k0 < 1024; k0 += 32) {
    const int cur = (k0 >> 5) & 1;
    if (k0 < 992) {
      STAGE(cur ^ 1, k0 + 32);
      __builtin_amdgcn_sched_barrier(0);
      asm volatile("s_waitcnt vmcnt(4)" ::: "memory");  // cur's 4 landed; next's 4 in flight
    } else {
      __builtin_amdgcn_sched_barrier(0);
      asm volatile("s_waitcnt vmcnt(0)" ::: "memory");
    }
    __builtin_amdgcn_sched_barrier(0);
    __builtin_amdgcn_s_barrier();
    __builtin_amdgcn_sched_barrier(0);

    const u16* Base = SMEM + cur * 8192;
    short8 af[4], bf[4];
#pragma unroll
    for (int rt = 0; rt < 4; ++rt) af[rt] = *(const short8*)(Base + afo[rt]);
#pragma unroll
    for (int ct = 0; ct < 4; ++ct) bf[ct] = *(const short8*)(Base + bfo[ct]);
    __builtin_amdgcn_s_setprio(1);
#pragma unroll
    for (int rt = 0; rt < 4; ++rt)
#pragma unroll
      for (int ct = 0; ct < 4; ++ct)
        c[rt][ct] = MFMA16(af[rt], bf[ct], c[rt][ct]);
    __builtin_amdgcn_s_setprio(0);
    __builtin_amdgcn_sched_barrier(0);
    __builtin_amdgcn_s_barrier();               // reads of cur done before its overwrite
    __builtin_amdgcn_sched_barrier(0);
  }
#undef STAGE

  const int which = n0 >> 10;                   // 0=q 1=k 2=v (block never crosses)
  if (which < 2) {
    u16* dst0 = which ? kW : qW;
    const float ksc = which ? 0.125f * LOG2E : 1.0f;
#pragma unroll
    for (int ct = 0; ct < 4; ++ct) {
      const int e = n0 + 64 * wn + 16 * ct + k15;
      const float bb = bin[e];
      const int h = (e >> 6) & 15, d = e & 63;
#pragma unroll
      for (int rt = 0; rt < 4; ++rt)
#pragma unroll
        for (int r = 0; r < 4; ++r) {
          const int m = m0 + 64 * wm + 16 * rt + 4 * quad + r;
          const int b = m >> 11, n = m & 2047;
          dst0[(((size_t)(b * 16 + h)) * 2048 + n) * 64 + d] = f2b((c[rt][ct][r] + bb) * ksc);
        }
    }
  } else {
    // v: gate, transpose 128x64 half-tiles through LDS -> vT[bh][d][2048]
    const int b = m0 >> 11, nbase = m0 & 2047;
    u16* T = SMEM;                              // 64 x 136 u16
    for (int half = 0; half < 2; ++half) {
      __syncthreads();
      if (wn == half) {
#pragma unroll
        for (int ct = 0; ct < 4; ++ct) {
          const int el = 16 * ct + k15;
          const int e = n0 + 64 * half + el;
          const float bb = bin[e];
#pragma unroll
          for (int rt = 0; rt < 4; ++rt)
#pragma unroll
            for (int r = 0; r < 4; ++r) {
              const int ml = 64 * wm + 16 * rt + 4 * quad + r;
              T[el * 136 + ml] = f2b((c[rt][ct][r] + bb) * vgate[nbase + ml]);
            }
        }
      }
      __syncthreads();
#pragma unroll
      for (int uu = 0; uu < 4; ++uu) {
        const int u = tid + uu * 256;
        const int el = u >> 4, moct = u & 15;
        const int e = n0 + 64 * half + el;
        const int h = (e >> 6) & 15, d = e & 63;
        short8 vv = *(const short8*)(T + el * 136 + moct * 8);
        *(short8*)(vT + (((size_t)(b * 16 + h)) * 64 + d) * 2048 + nbase + moct * 8) = vv;
      }
    }
  }
}

// ---------------- Flash attention v10 = v6/v8 structure ----------------
// K+V LDS DMA dbuf, counted vmcnt(4), shared Ps, ones-MFMA row-sum, defer-max,
// raw v_exp_f32, setprio; max-reduce in max3-fusable triplets. LDS = 40960 B.
__global__ __launch_bounds__(256, 4) void attn_mfma(
    const u16* __restrict__ qW, const u16* __restrict__ kW, const u16* __restrict__ vT,
    const float* __restrict__ colbias, u16* __restrict__ aO)
{
  __shared__ __align__(16) u16 Kbuf[2][4096];   // [key 64][d 64], swizzled, x2 dbuf
  __shared__ __align__(16) u16 Vbuf[2][4096];   // [d 64][key 64], swizzled, x2 dbuf
  __shared__ __align__(16) u16 Ps[4][1024];     // per-wave P [q 16][key 64], swizzled (reused per half)

  const int tid = threadIdx.x;
  const int wave = tid >> 6, lane = tid & 63;
  const int k15 = lane & 15, quad = lane >> 4;
  const int bid = blockIdx.x;
  const int bh = bid & 63, qt = bid >> 6;       // XCD-affine: all 16 q-tiles of bh on one XCD
  const size_t base = (size_t)bh * 2048 * 64;
  const size_t baseV = (size_t)bh * 64 * 2048;
  const int q0 = qt * 128 + wave * 32;

  // swizzle constants (u16 units). phys_col = logical_col ^ ((row&7)<<3)
  const int sw3 = (k15 & 7) << 3;
  const int cA = (quad * 8) ^ sw3;              // logical chunk 0..31
  const int cB = (quad * 8 + 32) ^ sw3;         // logical chunk 32..63

  // DMA staging addressing: lane fetches the global chunk for its linear LDS slot
  const int krow0 = wave * 16 + (lane >> 3);    // wave w stages rows 16w..16w+15
  const int swz = ((lane & 7) * 8) ^ ((lane >> 3) << 3);
  const u16* gK = kW + base + (size_t)krow0 * 64 + swz;
  const u16* gV = vT + baseV + (size_t)krow0 * 2048 + swz;

#define STAGE(nb, kbn) do {                                                    \
    gload16(gK + (size_t)(kbn) * 64, &Kbuf[nb][wave * 1024]);                  \
    gload16(gK + (size_t)(kbn) * 64 + 512, &Kbuf[nb][wave * 1024 + 512]);      \
    gload16(gV + (kbn), &Vbuf[nb][wave * 1024]);                               \
    gload16(gV + (kbn) + 8 * 2048, &Vbuf[nb][wave * 1024 + 512]);              \
  } while (0)

  // Q fragments (B operand): col=q, k=d
  const u16* qp = qW + base + (size_t)(q0 + k15) * 64 + quad * 8;
  short8 qa00 = *(const short8*)qp;             // h0, d 0..31
  short8 qa01 = *(const short8*)(qp + 32);      // h0, d 32..63
  short8 qa10 = *(const short8*)(qp + 16 * 64); // h1
  short8 qa11 = *(const short8*)(qp + 16 * 64 + 32);

  floatx4 o0[4], o1[4];
#pragma unroll
  for (int t = 0; t < 4; ++t) {
    o0[t] = (floatx4){0.f, 0.f, 0.f, 0.f};
    o1[t] = (floatx4){0.f, 0.f, 0.f, 0.f};
  }
  floatx4 l0 = (floatx4){0.f, 0.f, 0.f, 0.f};
  floatx4 l1 = (floatx4){0.f, 0.f, 0.f, 0.f};
  float m0 = -3.0e38f, m1 = -3.0e38f;

  u16* PsW = Ps[wave];
  const short8 ones8 = (short8){16256, 16256, 16256, 16256, 16256, 16256, 16256, 16256};

  STAGE(0, 0);                                  // prologue K(0)/V(0)

  for (int kb = 0; kb < 2048; kb += 64) {
    const int cur = (kb >> 6) & 1;

    // colbias for this tile (issued before next-tile DMA so vmcnt(4) drains them)
    float4 cb[4];
#pragma unroll
    for (int t = 0; t < 4; ++t)
      cb[t] = *(const float4*)(colbias + kb + 16 * t + 4 * quad);
    __builtin_amdgcn_sched_barrier(0);
    if (kb < 1984) {
      STAGE(cur ^ 1, kb + 64);
      asm volatile("s_waitcnt vmcnt(4)" ::: "memory");  // cur's 4 + cb done; next's 4 in flight
    } else {
      asm volatile("s_waitcnt vmcnt(0)" ::: "memory");
    }
    __builtin_amdgcn_sched_barrier(0);
    __builtin_amdgcn_s_barrier();               // all waves' cur-tile DMA landed
    __builtin_amdgcn_sched_barrier(0);

    const u16* Kc = Kbuf[cur];
    const u16* Vc = Vbuf[cur];

    // S^T = K.Q^T for both q-halves; K frags shared, loaded per-t
    floatx4 s0[4], s1[4];
    __builtin_amdgcn_s_setprio(1);
#pragma unroll
    for (int t = 0; t < 4; ++t) {
      const u16* kp = Kc + (16 * t + k15) * 64;
      short8 ka0 = *(const short8*)(kp + cA);
      short8 ka1 = *(const short8*)(kp + cB);
      floatx4 ci = (floatx4){cb[t].x, cb[t].y, cb[t].z, cb[t].w};
      s0[t] = MFMA16(ka0, qa00, ci);
      s0[t] = MFMA16(ka1, qa01, s0[t]);
      s1[t] = MFMA16(ka0, qa10, ci);
      s1[t] = MFMA16(ka1, qa11, s1[t]);
    }
    __builtin_amdgcn_s_setprio(0);

    // per-lane softmax (log2 domain), defer-max (THR=8), pack P -> per-wave LDS
    // max-reduce in max3-fusable triplet nesting (clang fuses fmaxf(fmaxf(a,b),c))
#define SOFTHALF(S, M, L, O) do {                                              \
    float a0_ = fmaxf(fmaxf(S[0][0], S[0][1]), S[0][2]);                       \
    float a1_ = fmaxf(fmaxf(S[0][3], S[1][0]), S[1][1]);                       \
    float a2_ = fmaxf(fmaxf(S[1][2], S[1][3]), S[2][0]);                       \
    float a3_ = fmaxf(fmaxf(S[2][1], S[2][2]), S[2][3]);                       \
    float a4_ = fmaxf(fmaxf(S[3][0], S[3][1]), S[3][2]);                       \
    float b0_ = fmaxf(fmaxf(a0_, a1_), a2_);                                   \
    float b1_ = fmaxf(fmaxf(a3_, a4_), S[3][3]);                               \
    float mx = fmaxf(b0_, b1_);                                                \
    mx = fmaxf(mx, __shfl_xor(mx, 16));                                        \
    mx = fmaxf(mx, __shfl_xor(mx, 32));                                        \
    if (__any(mx > (M) + 8.0f)) {                                              \
      const float mn = fmaxf(M, mx);                                           \
      const float al = fexp2((M) - mn);                                        \
      M = mn;                                                                  \
      const float a0 = __shfl(al, 4 * quad + 0);                               \
      const float a1 = __shfl(al, 4 * quad + 1);                               \
      const float a2 = __shfl(al, 4 * quad + 2);                               \
      const float a3 = __shfl(al, 4 * quad + 3);                               \
      L[0] *= a0; L[1] *= a1; L[2] *= a2; L[3] *= a3;                          \
      _Pragma("unroll") for (int t = 0; t < 4; ++t) {                          \
        O[t][0] *= a0; O[t][1] *= a1; O[t][2] *= a2; O[t][3] *= a3;            \
      }                                                                        \
    }                                                                          \
    _Pragma("unroll") for (int t = 0; t < 4; ++t) {                            \
      float p0 = fexp2(S[t][0] - M), p1 = fexp2(S[t][1] - M);                  \
      float p2 = fexp2(S[t][2] - M), p3 = fexp2(S[t][3] - M);                  \
      u32 lo = __builtin_amdgcn_perm(__float_as_uint(p1), __float_as_uint(p0), 0x07060302u); \
      u32 hi = __builtin_amdgcn_perm(__float_as_uint(p3), __float_as_uint(p2), 0x07060302u); \
      *(uint2*)(PsW + k15 * 64 + ((16 * t + 4 * quad) ^ sw3)) = (uint2){lo, hi}; \
    }                                                                          \
  } while (0)

    SOFTHALF(s0, m0, l0, o0);
    short8 pa00 = *(const short8*)(PsW + k15 * 64 + cA);
    short8 pa01 = *(const short8*)(PsW + k15 * 64 + cB);
    {
      floatx4 z4 = (floatx4){0.f, 0.f, 0.f, 0.f};
      floatx4 sA = MFMA16(pa00, ones8, z4);     // row-sum on the MFMA pipe (D-layout)
      sA = MFMA16(pa01, ones8, sA);
      l0 += sA;
    }
    SOFTHALF(s1, m1, l1, o1);
    short8 pa10 = *(const short8*)(PsW + k15 * 64 + cA);
    short8 pa11 = *(const short8*)(PsW + k15 * 64 + cB);
    {
      floatx4 z4 = (floatx4){0.f, 0.f, 0.f, 0.f};
      floatx4 sB = MFMA16(pa10, ones8, z4);
      sB = MFMA16(pa11, ones8, sB);
      l1 += sB;
    }

    // O += P.V  (V frags from LDS, per-t lifetime; shared across halves)
    __builtin_amdgcn_s_setprio(1);
#pragma unroll
    for (int t = 0; t < 4; ++t) {
      const u16* vp = Vc + (16 * t + k15) * 64;
      short8 vb0 = *(const short8*)(vp + cA);
      short8 vb1 = *(const short8*)(vp + cB);
      o0[t] = MFMA16(pa00, vb0, o0[t]);
      o0[t] = MFMA16(pa01, vb1, o0[t]);
      o1[t] = MFMA16(pa10, vb0, o1[t]);
      o1[t] = MFMA16(pa11, vb1, o1[t]);
    }
    __builtin_amdgcn_s_setprio(0);
    __builtin_amdgcn_sched_barrier(0);
    __builtin_amdgcn_s_barrier();               // all reads of cur done before its overwrite
    __builtin_amdgcn_sched_barrier(0);
  }
#undef SOFTHALF
#undef STAGE

  // epilogue: l already in D-layout; normalize, store aO [b][n][h*64+d]
  const int b = bh >> 4, h = bh & 15;
#pragma unroll
  for (int r = 0; r < 4; ++r) {
    {
      const int q = q0 + 4 * quad + r;
      const float inv = 1.0f / l0[r];
      u16* dst = aO + (size_t)(b * 2048 + q) * 1024 + h * 64;
#pragma unroll
      for (int t = 0; t < 4; ++t) dst[16 * t + k15] = f2b(o0[t][r] * inv);
    }
    {
      const int q = q0 + 16 + 4 * quad + r;
      const float inv = 1.0f / l1[r];
      u16* dst = aO + (size_t)(b * 2048 + q) * 1024 + h * 64;
#pragma unroll
      for (int t = 0; t < 4; ++t) dst[16 * t + k15] = f2b(o1[t][r] * inv);
    }
  }
}

// ---------------- Output projection v2: BM=64 x BN=128, 4 blocks/CU ----------------
// REQUIRES grid (8, 128): m0 = blockIdx.y*64 covers 8192 rows.
__global__ __launch_bounds__(256, 4) void oproj_mfma(
    const u16* __restrict__ A, const u16* __restrict__ Wob, const float* __restrict__ bout,
    float* __restrict__ out)
{
  __shared__ __align__(16) u16 SMEM[12288];     // 24 KB: [2][As 2048 | Bs 4096]
  const int tid = threadIdx.x;
  const int wave = tid >> 6, lane = tid & 63;
  const int k15 = lane & 15, quad = lane >> 4;
  const int m0 = blockIdx.y << 6, n0 = blockIdx.x << 7;

  const int line = lane >> 3;
  const int sl = (lane & 7) ^ line;
  const int rloc = (line << 1) | (sl >> 2);
  const int cch = (sl & 3) << 3;
  const u16* gA = A + (size_t)(m0 + (wave << 4) + rloc) * 1024 + cch;   // wave stages 16 A-rows
  const u16* gB = Wob + (size_t)(n0 + (wave << 5) + rloc) * 1024 + cch; // wave stages 32 B-rows

#define STAGE(buf, k0s) do {                                                   \
    u16* b_ = SMEM + (buf) * 6144;                                             \
    gload16(gA + (k0s), b_ + (wave << 9));                                     \
    gload16(gB + (k0s), b_ + 2048 + (wave << 10));                             \
    gload16(gB + (k0s) + 16 * 1024, b_ + 2048 + (wave << 10) + 512);           \
  } while (0)

  // loop-invariant frag LDS offsets (A rows 0..63; B rows = wave's 32 cols)
  int afo[4], bfo[2];
#pragma unroll
  for (int rt = 0; rt < 4; ++rt) afo[rt] = swzg(16 * rt + k15, quad);
#pragma unroll
  for (int ct = 0; ct < 2; ++ct) bfo[ct] = 2048 + swzg((wave << 5) + 16 * ct + k15, quad);

  floatx4 c[4][2];
#pragma unroll
  for (int i = 0; i < 4; ++i)
#pragma unroll
    for (int j = 0; j < 2; ++j) c[i][j] = (floatx4){0.f, 0.f, 0.f, 0.f};

  STAGE(0, 0);
  for (int k0 = 0; k0 < 1024; k0 += 32) {
    const int cur = (k0 >> 5) & 1;
    if (k0 < 992) {
      STAGE(cur ^ 1, k0 + 32);
      __builtin_amdgcn_sched_barrier(0);
      asm volatile("s_waitcnt vmcnt(3)" ::: "memory");  // cur's 3 landed; next's 3 in flight
    } else {
      __builtin_amdgcn_sched_barrier(0);
      asm volatile("s_waitcnt vmcnt(0)" ::: "memory");
    }
    __builtin_amdgcn_sched_barrier(0);
    __builtin_amdgcn_s_barrier();
    __builtin_amdgcn_sched_barrier(0);

    const u16* Base = SMEM + cur * 6144;
    short8 af[4], bf[2];
#pragma unroll
    for (int rt = 0; rt < 4; ++rt) af[rt] = *(const short8*)(Base + afo[rt]);
#pragma unroll
    for (int ct = 0; ct < 2; ++ct) bf[ct] = *(const short8*)(Base + bfo[ct]);
    __builtin_amdgcn_s_setprio(1);
#pragma unroll
    for (int rt = 0; rt < 4; ++rt)
#pragma unroll
      for (int ct = 0; ct < 2; ++ct)
        c[rt][ct] = MFMA16(af[rt], bf[ct], c[rt][ct]);
    __builtin_amdgcn_s_setprio(0);
    __builtin_amdgcn_sched_barrier(0);
    __builtin_amdgcn_s_barrier();
    __builtin_amdgcn_sched_barrier(0);
  }
#undef STAGE

#pragma unroll
  for (int ct = 0; ct < 2; ++ct) {
    const int e = n0 + (wave << 5) + 16 * ct + k15;
    const float bb = bout[e];
#pragma unroll
    for (int rt = 0; rt < 4; ++rt)
#pragma unroll
      for (int r = 0; r < 4; ++r) {
        const int m = m0 + 16 * rt + 4 * quad + r;
        out[(size_t)m * 1024 + e] = c[rt][ct][r] + bb;
      }
  }
}

extern "C" void kernel_launch(void* const* d_in, const int* in_sizes, int n_in,
                              void* d_out, int out_size, void* d_ws, size_t ws_size,
                              hipStream_t stream)
{
  const float* X     = (const float*)d_in[0];
  const int*   pnc   = (const int*)d_in[1];
  const float* ppr   = (const float*)d_in[2];
  const float* trust = (const float*)d_in[3];
  const float* Win   = (const float*)d_in[4];
  const float* bin   = (const float*)d_in[5];
  const float* Wout  = (const float*)d_in[6];
  const float* bout  = (const float*)d_in[7];
  const float* plpa  = (const float*)d_in[8];
  const float* ptsc  = (const float*)d_in[9];
  float* out = (float*)d_out;

  const size_t SZ = (size_t)64 * 2048 * 64;     // 8,388,608 elems = 16 MB bf16
  u16* Xb = (u16*)d_ws;                         // phase 1-2; aliased by aO in phase 3+
  u16* qW = Xb + SZ;
  u16* kW = qW + SZ;                            // phase 3; aliased by Wob in phase 4+
  u16* vT = kW + SZ;                            // [bh][d][2048]   (total ws = 64 MB)
  u16* aO = Xb;
  u16* Wob = kW;
  // scratch parked in d_out (fully overwritten by oproj at the end):
  float* colbias = (float*)d_out;               // [2048] (log2-domain)
  float* vgate   = colbias + 2048;              // [2048]
  u16*   Wib     = (u16*)(vgate + 2048);        // 3072x1024 bf16 = 6 MB

  prep_kernel<<<dim3(8), 256, 0, stream>>>(ppr, trust, plpa, ptsc, pnc, colbias, vgate);
  convert1<<<dim3(5632), 256, 0, stream>>>(X, Win, Xb, Wib);
  qkv_mfma<<<dim3(24, 64), 256, 0, stream>>>(Xb, Wib, bin, vgate, qW, kW, vT);
  attn_mfma<<<dim3(1024), 256, 0, stream>>>(qW, kW, vT, colbias, aO);
  convert2<<<dim3(512), 256, 0, stream>>>(Wout, Wob);
  oproj_mfma<<<dim3(8, 128), 256, 0, stream>>>(aO, Wob, bout, out);
}